// Round 1
// baseline (506.961 us; speedup 1.0000x reference)
//
#include <hip/hip_runtime.h>
#include <hip/hip_bf16.h>

typedef __attribute__((ext_vector_type(8))) short short8;
typedef __attribute__((ext_vector_type(4))) float floatx4;

#define SCALE_Q 0.17677669529663687f

__device__ __forceinline__ short f2bf(float f) {
  union { float f; unsigned u; } a; a.f = f;
  unsigned r = (a.u + 0x7FFFu + ((a.u >> 16) & 1u)) >> 16;
  return (short)r;
}

// ---------- weight transpose + bf16: dst[n*K+k] = src[k*N+n] ----------
__global__ void transpose_w_k(const float* __restrict__ src, short* __restrict__ dst,
                              int K, int N) {
  int i = blockIdx.x * 256 + threadIdx.x;
  if (i >= N * K) return;
  int n = i / K, k = i - n * K;
  dst[i] = f2bf(src[(size_t)k * N + n]);
}

// ---------- fused pos_bias + shifted-window mask table: bm[w][h][49][49] ----------
__global__ void prep_bm_k(const float* __restrict__ pos_bias, float* __restrict__ bm) {
  int i = blockIdx.x * 256 + threadIdx.x;
  if (i >= 64 * 6 * 49 * 49) return;
  int j = i % 49; int t = i / 49; int ii = t % 49; t /= 49; int h = t % 6; int w = t / 6;
  int ih = ii / 7, iw = ii - ih * 7, jh = j / 7, jw = j - jh * 7;
  int rel = (ih - jh + 6) * 13 + (iw - jw + 6);
  float v = pos_bias[rel * 6 + h];
  int wh = w >> 3, ww = w & 7;
  int ri = wh * 7 + ih, ci = ww * 7 + iw, rj = wh * 7 + jh, cj = ww * 7 + jw;
  int regi = ((ri >= 49) + (ri >= 53)) * 3 + ((ci >= 49) + (ci >= 53));
  int regj = ((rj >= 49) + (rj >= 53)) * 3 + ((cj >= 49) + (cj >= 53));
  if (regi != regj) v -= 100.0f;
  bm[i] = v;
}

// ---------- LayerNorm (one wave per 192-elem row), SHIFT=1 adds roll+window map ----------
template<int SHIFT>
__global__ __launch_bounds__(256) void ln_k(const float* __restrict__ x,
    const float* __restrict__ g, const float* __restrict__ bta,
    short* __restrict__ outb) {
  int wid = threadIdx.x >> 6, lane = threadIdx.x & 63;
  int r = blockIdx.x * 4 + wid;
  size_t src;
  if (SHIFT) {
    int n = r / 49, tw = r - n * 49;
    int bb = n >> 6, wdx = n & 63;
    int rh = (wdx >> 3) * 7 + tw / 7, rw = (wdx & 7) * 7 + tw % 7;
    int sh = rh + 3; if (sh >= 56) sh -= 56;
    int sw = rw + 3; if (sw >= 56) sw -= 56;
    src = ((size_t)bb * 3136 + sh * 56 + sw) * 192;
  } else {
    src = (size_t)r * 192;
  }
  const float* xr = x + src;
  float v0 = xr[lane], v1 = xr[lane + 64], v2 = xr[lane + 128];
  float s = v0 + v1 + v2, sq = v0 * v0 + v1 * v1 + v2 * v2;
  #pragma unroll
  for (int o = 32; o >= 1; o >>= 1) { s += __shfl_xor(s, o); sq += __shfl_xor(sq, o); }
  float mean = s * (1.0f / 192.0f);
  float rstd = rsqrtf(sq * (1.0f / 192.0f) - mean * mean + 1e-5f);
  short* orow = outb + (size_t)r * 192;
  orow[lane]       = f2bf((v0 - mean) * rstd * g[lane]       + bta[lane]);
  orow[lane + 64]  = f2bf((v1 - mean) * rstd * g[lane + 64]  + bta[lane + 64]);
  orow[lane + 128] = f2bf((v2 - mean) * rstd * g[lane + 128] + bta[lane + 128]);
}

// ---------- generic bf16 MFMA GEMM, 128x64 tile, 4 waves, templated epilogue ----------
// A [M,K] bf16 row-major; Bt [N,K] bf16 (pre-transposed weights); fp32 accumulate.
// EPI 0: QKV scatter  1: proj+reverse-shift+residual  2: +gelu->hidden  3: +x1 accumulate
template<int EPI>
__global__ __launch_bounds__(256) void gemm_k(
    const short* __restrict__ A, const short* __restrict__ Bt,
    const float* __restrict__ bias, void* __restrict__ outp,
    const void* __restrict__ aux, int N, int K) {
  __shared__ short As[128][72];   // stride 144B = 9*16B -> 2-way conflicts only
  __shared__ short Bs[64][72];
  int tid = threadIdx.x;
  int gmb = blockIdx.y * 128;
  int gnb = blockIdx.x * 64;
  int wid = tid >> 6, lane = tid & 63;
  int wm = wid >> 1, wn = wid & 1;
  int lr = lane & 15, lk = (lane >> 4) << 3, lq = (lane >> 4) << 2;
  floatx4 acc[4][2];
  #pragma unroll
  for (int i = 0; i < 4; ++i)
    #pragma unroll
    for (int j = 0; j < 2; ++j) acc[i][j] = (floatx4)(0.0f);

  for (int k0 = 0; k0 < K; k0 += 64) {
    #pragma unroll
    for (int i = 0; i < 4; ++i) {
      int u = tid + 256 * i;
      int row = u >> 3, cb = (u & 7) << 3;
      *(short8*)&As[row][cb] = *(const short8*)&A[(size_t)(gmb + row) * K + k0 + cb];
    }
    #pragma unroll
    for (int i = 0; i < 2; ++i) {
      int u = tid + 256 * i;
      int row = u >> 3, cb = (u & 7) << 3;
      *(short8*)&Bs[row][cb] = *(const short8*)&Bt[(size_t)(gnb + row) * K + k0 + cb];
    }
    __syncthreads();
    #pragma unroll
    for (int kk = 0; kk < 64; kk += 32) {
      short8 af[4], bfr[2];
      #pragma unroll
      for (int mi = 0; mi < 4; ++mi)
        af[mi] = *(const short8*)&As[wm * 64 + mi * 16 + lr][kk + lk];
      #pragma unroll
      for (int ni = 0; ni < 2; ++ni)
        bfr[ni] = *(const short8*)&Bs[wn * 32 + ni * 16 + lr][kk + lk];
      #pragma unroll
      for (int mi = 0; mi < 4; ++mi)
        #pragma unroll
        for (int ni = 0; ni < 2; ++ni)
          acc[mi][ni] = __builtin_amdgcn_mfma_f32_16x16x32_bf16(af[mi], bfr[ni], acc[mi][ni], 0, 0, 0);
    }
    __syncthreads();
  }

  #pragma unroll
  for (int mi = 0; mi < 4; ++mi) {
    #pragma unroll
    for (int ni = 0; ni < 2; ++ni) {
      #pragma unroll
      for (int r = 0; r < 4; ++r) {
        int grow = gmb + wm * 64 + mi * 16 + lq + r;
        int gcol = gnb + wn * 32 + ni * 16 + lr;
        float v = acc[mi][ni][r] + bias[gcol];
        if (EPI == 0) {
          int which = gcol / 192, rem = gcol - which * 192;
          if (which == 0) v *= SCALE_Q;
          int head = rem >> 5, d = rem & 31;
          int n = grow / 49, tw = grow - n * 49;
          ((short*)outp)[((((size_t)(n * 6 + head) * 3 + which) * 49 + tw) << 5) + d] = f2bf(v);
        } else if (EPI == 1) {
          int n = grow / 49, tw = grow - n * 49;
          int bb = n >> 6, wdx = n & 63;
          int rh = (wdx >> 3) * 7 + tw / 7, rw = (wdx & 7) * 7 + tw % 7;
          int oh = rh + 3; if (oh >= 56) oh -= 56;
          int ow = rw + 3; if (ow >= 56) ow -= 56;
          size_t idx = ((size_t)bb * 3136 + oh * 56 + ow) * 192 + gcol;
          ((float*)outp)[idx] = ((const float*)aux)[idx] + v;   // x1 = x + o
        } else if (EPI == 2) {
          float ge = 0.5f * v * (1.0f + erff(v * 0.70710678118f));
          ((short*)outp)[(size_t)grow * 768 + gcol] = f2bf(ge);
        } else {
          size_t idx = (size_t)grow * 192 + gcol;
          ((float*)outp)[idx] += v;                              // out = x1 + m
        }
      }
    }
  }
}

// ---------- window attention core: 1 wave per (window, head), NO softmax ----------
__global__ __launch_bounds__(256) void attn_k(const short* __restrict__ qkv,
    const float* __restrict__ bm, short* __restrict__ obuf) {
  __shared__ short lds[4][6912];          // per wave: Vt[32][72] + Ps[64][72]
  int wid = threadIdx.x >> 6, lane = threadIdx.x & 63;
  int pair = blockIdx.x * 4 + wid;
  int n = pair / 6, h = pair - n * 6;
  short* Vt = &lds[wid][0];
  short* Ps = &lds[wid][32 * 72];
  const short* Qb = qkv + (size_t)((n * 6 + h) * 3) * 1568;
  const short* Kb = Qb + 1568;
  const short* Vb = Qb + 3136;
  int lr = lane & 15, lk = (lane >> 4) << 3, lq = (lane >> 4) << 2;

  // zero pad columns 48..63 of Vt (keys >= 49); P is 0 there so any finite value is fine,
  // but LDS poison could be NaN -> must clear.
  #pragma unroll
  for (int it = 0; it < 8; ++it) {
    int u = lane + 64 * it;
    Vt[(u >> 4) * 72 + 48 + (u & 15)] = 0;
  }
  // stage V transposed: Vt[d][key]
  #pragma unroll
  for (int it = 0; it < 4; ++it) {
    int u = lane + 64 * it;
    if (u < 196) {
      int tw = u >> 2, db = (u & 3) << 3;
      short8 vv = *(const short8*)&Vb[tw * 32 + db];
      #pragma unroll
      for (int j = 0; j < 8; ++j) Vt[(db + j) * 72 + tw] = vv[j];
    }
  }

  // S = Q K^T   (Q pre-scaled; fragment loads straight from global — rows >=49 read
  // garbage from the adjacent matrix, overwritten with 0 below)
  short8 qf[4], kf[4];
  #pragma unroll
  for (int mi = 0; mi < 4; ++mi)
    qf[mi] = *(const short8*)&Qb[(mi * 16 + lr) * 32 + lk];
  #pragma unroll
  for (int nj = 0; nj < 4; ++nj)
    kf[nj] = *(const short8*)&Kb[(nj * 16 + lr) * 32 + lk];
  floatx4 s[4][4];
  #pragma unroll
  for (int mi = 0; mi < 4; ++mi)
    #pragma unroll
    for (int nj = 0; nj < 4; ++nj)
      s[mi][nj] = __builtin_amdgcn_mfma_f32_16x16x32_bf16(qf[mi], kf[nj], (floatx4)(0.0f), 0, 0, 0);

  // P = S + bias + mask in valid 49x49, else 0 -> bf16 -> LDS (transpose for PV A-operand)
  const float* bmw = bm + (size_t)((n & 63) * 6 + h) * 2401;
  #pragma unroll
  for (int mi = 0; mi < 4; ++mi)
    #pragma unroll
    for (int nj = 0; nj < 4; ++nj)
      #pragma unroll
      for (int r = 0; r < 4; ++r) {
        int i = mi * 16 + lq + r;
        int j = nj * 16 + lr;
        float v = 0.0f;
        if (i < 49 && j < 49) v = s[mi][nj][r] + bmw[i * 49 + j];
        Ps[i * 72 + j] = f2bf(v);
      }

  // O = P V
  floatx4 o[4][2];
  #pragma unroll
  for (int mi = 0; mi < 4; ++mi)
    #pragma unroll
    for (int ni = 0; ni < 2; ++ni) o[mi][ni] = (floatx4)(0.0f);
  #pragma unroll
  for (int kc = 0; kc < 2; ++kc) {
    short8 pf[4], vf[2];
    #pragma unroll
    for (int mi = 0; mi < 4; ++mi)
      pf[mi] = *(const short8*)&Ps[(mi * 16 + lr) * 72 + kc * 32 + lk];
    #pragma unroll
    for (int ni = 0; ni < 2; ++ni)
      vf[ni] = *(const short8*)&Vt[(ni * 16 + lr) * 72 + kc * 32 + lk];
    #pragma unroll
    for (int mi = 0; mi < 4; ++mi)
      #pragma unroll
      for (int ni = 0; ni < 2; ++ni)
        o[mi][ni] = __builtin_amdgcn_mfma_f32_16x16x32_bf16(pf[mi], vf[ni], o[mi][ni], 0, 0, 0);
  }
  #pragma unroll
  for (int mi = 0; mi < 4; ++mi)
    #pragma unroll
    for (int ni = 0; ni < 2; ++ni)
      #pragma unroll
      for (int r = 0; r < 4; ++r) {
        int i = mi * 16 + lq + r;
        if (i < 49)
          obuf[((size_t)n * 49 + i) * 192 + h * 32 + ni * 16 + lr] = f2bf(o[mi][ni][r]);
      }
}

extern "C" void kernel_launch(void* const* d_in, const int* in_sizes, int n_in,
                              void* d_out, int out_size, void* d_ws, size_t ws_size,
                              hipStream_t stream) {
  const float* x      = (const float*)d_in[0];
  const float* ln1_g  = (const float*)d_in[1];
  const float* ln1_b  = (const float*)d_in[2];
  const float* qkv_w  = (const float*)d_in[3];
  const float* qkv_b  = (const float*)d_in[4];
  const float* pos_b  = (const float*)d_in[5];
  const float* proj_w = (const float*)d_in[6];
  const float* proj_b = (const float*)d_in[7];
  const float* ln2_g  = (const float*)d_in[8];
  const float* ln2_b  = (const float*)d_in[9];
  const float* mlp_w1 = (const float*)d_in[10];
  const float* mlp_b1 = (const float*)d_in[11];
  const float* mlp_w2 = (const float*)d_in[12];
  const float* mlp_b2 = (const float*)d_in[13];

  // workspace layout (bytes). hidden aliases qkvbuf+obuf (both dead by MLP1);
  // ln2 output aliases hbuf (dead after QKV GEMM). Peak use ~197 MB.
  char* ws = (char*)d_ws;
  short* qkvbuf  = (short*)(ws);                 // [2048][6][3][49][32] bf16 = 115,605,504 B
  short* obuf    = (short*)(ws + 115605504);     // [100352][192] bf16    =  38,535,168 B
  short* hidden  = (short*)(ws);                 // [100352][768] bf16 (alias, 154,140,672 B)
  short* hbuf    = (short*)(ws + 154140672);     // [100352][192] bf16 (ln1 out / ln2 out)
  short* wT      = (short*)(ws + 192675840);     // transposed bf16 weights
  short* qkv_wT  = wT;                            // 576*192
  short* proj_wT = wT + 110592;                   // 192*192
  short* m1_wT   = wT + 110592 + 36864;           // 768*192
  short* m2_wT   = wT + 110592 + 36864 + 147456;  // 192*768
  float* bm      = (float*)(ws + 193560576);      // [64][6][49][49] f32 = 3,687,936 B
  float* xout    = (float*)d_out;                 // x1 then final output

  transpose_w_k<<<(110592 + 255) / 256, 256, 0, stream>>>(qkv_w,  qkv_wT, 192, 576);
  transpose_w_k<<<(36864  + 255) / 256, 256, 0, stream>>>(proj_w, proj_wT, 192, 192);
  transpose_w_k<<<(147456 + 255) / 256, 256, 0, stream>>>(mlp_w1, m1_wT,  192, 768);
  transpose_w_k<<<(147456 + 255) / 256, 256, 0, stream>>>(mlp_w2, m2_wT,  768, 192);
  prep_bm_k<<<(64 * 6 * 2401 + 255) / 256, 256, 0, stream>>>(pos_b, bm);

  ln_k<1><<<25088, 256, 0, stream>>>(x, ln1_g, ln1_b, hbuf);                 // LN1+shift+window
  gemm_k<0><<<dim3(9, 784),  256, 0, stream>>>(hbuf, qkv_wT, qkv_b, qkvbuf, nullptr, 576, 192);
  attn_k<<<3072, 256, 0, stream>>>(qkvbuf, bm, obuf);
  gemm_k<1><<<dim3(3, 784),  256, 0, stream>>>(obuf, proj_wT, proj_b, xout, x, 192, 192);
  ln_k<0><<<25088, 256, 0, stream>>>(xout, ln2_g, ln2_b, hbuf);              // LN2 on x1
  gemm_k<2><<<dim3(12, 784), 256, 0, stream>>>(hbuf, m1_wT, mlp_b1, hidden, nullptr, 768, 192);
  gemm_k<3><<<dim3(3, 784),  256, 0, stream>>>(hidden, m2_wT, mlp_b2, xout, nullptr, 192, 768);
}